// Round 4
// baseline (316.418 us; speedup 1.0000x reference)
//
#include <hip/hip_runtime.h>

// B=32, D=128, K=32, N=9216. Fused softmax(scaled-L2)+aggregation, bf16 MFMA.
// Deterministic: per-block partials in d_ws + reduction kernel (no atomics).
// R4: wave-local GEMM1 staging (no barrier), in-register x2, 2 barriers/sub-chunk.
#define B_ 32
#define D_ 128
#define K_ 32
#define N_ 9216
#define NT 256      // n per block
#define NS 64       // n per sub-chunk
#define XDN_S 72    // X_dn row stride (bf16 shorts) -> 144 B
#define AKN_S 72    // A_kn row stride
// X_nd / CWb: stride 128 shorts, 16B-granule XOR swizzle: phys_g = g ^ (row&15)

typedef __bf16 bf16x8_t __attribute__((ext_vector_type(8)));
typedef float f32x4_t __attribute__((ext_vector_type(4)));

__device__ __forceinline__ unsigned short f2bf(float f) {
    unsigned u = __float_as_uint(f);
    u = (u + 0x7fffu + ((u >> 16) & 1u)) >> 16;
    return (unsigned short)u;
}
__device__ __forceinline__ unsigned f2bf_pk(float lo, float hi) {
    unsigned a = __float_as_uint(lo);
    a = (a + 0x7fffu + ((a >> 16) & 1u)) >> 16;
    unsigned b = __float_as_uint(hi);
    b = (b + 0x7fffu + ((b >> 16) & 1u)) & 0xffff0000u;
    return a | b;
}

__global__ __launch_bounds__(256, 3) void k_fused(
        const float* __restrict__ X, const float* __restrict__ cw,
        const float* __restrict__ scale, float* __restrict__ ws) {
    __shared__ __align__(16) unsigned short X_nd[NS * 128];     // 16384 B (swizzled)
    __shared__ __align__(16) unsigned short X_dn[D_ * XDN_S];   // 18432 B
    __shared__ __align__(16) unsigned short CWb[K_ * 128];      //  8192 B (swizzled)
    __shared__ __align__(16) unsigned short Akn[K_ * AKN_S];    //  4608 B
    __shared__ float u_s[K_], w_s[K_];
    __shared__ float sAw[4 * 34];
    __shared__ float sA[K_];

    const int t = threadIdx.x;
    const int w = t >> 6;          // wave 0..3
    const int l = t & 63;          // lane
    const int lm = l & 15;
    const int lq = l >> 4;         // 0..3
    const int nq = l & 3;          // staging: n-quad within wave's 16-n range
    const int dgrp = l >> 2;       // staging: d-octet 0..15
    const int b = blockIdx.x / 36;
    const int n0 = (blockIdx.x % 36) * NT;

    // ---- stage codewords -> bf16 LDS (swizzled granules) ----
    #pragma unroll
    for (int i = 0; i < 4; ++i) {
        int idx = t + 256 * i;                 // float4 id, 1024 total
        int k = idx >> 5, d4 = idx & 31;
        float4 c = ((const float4*)cw)[idx];
        int phys = (d4 >> 1) ^ (k & 15);
        unsigned* p = (unsigned*)&CWb[k * 128 + phys * 8 + (d4 & 1) * 4];
        p[0] = f2bf_pk(c.x, c.y);
        p[1] = f2bf_pk(c.z, c.w);
    }
    if (t < 32) {
        float sc = scale[t];
        float s2 = sc * sc;
        const float4* cr = (const float4*)(cw + t * 128);
        float c2 = 0.f;
        #pragma unroll 8
        for (int i = 0; i < 32; ++i) {
            float4 v = cr[i];
            c2 += v.x * v.x + v.y * v.y + v.z * v.z + v.w * v.w;
        }
        u_s[t] = s2;
        w_s[t] = s2 * c2;
    }
    __syncthreads();
    const float u0 = u_s[lm], u1 = u_s[16 + lm];
    const float w0 = w_s[lm], w1 = w_s[16 + lm];

    f32x4_t acc2[2][2];
    #pragma unroll
    for (int a = 0; a < 2; ++a)
        #pragma unroll
        for (int c = 0; c < 2; ++c)
            acc2[a][c] = (f32x4_t){0.f, 0.f, 0.f, 0.f};
    float ps0 = 0.f, ps1 = 0.f;

    for (int s = 0; s < 4; ++s) {
        __syncthreads();   // prev GEMM2 done reading X_dn/Akn before restage
        // ---- wave-local staging: wave w loads n = n0+s*64+w*16+nq*4..+3,
        //      d = dgrp*8..+7 (full 128 d within the wave) ----
        const float* Xg = X + (size_t)b * (D_ * (size_t)N_) + n0 + s * NS + w * 16 + nq * 4;
        float4 v[8];
        #pragma unroll
        for (int j = 0; j < 8; ++j)
            v[j] = *(const float4*)(Xg + (size_t)(dgrp * 8 + j) * N_);
        // x2 in-register: partial over 8 d, reduce across 16 dgrp lanes
        float x2p[4];
        #pragma unroll
        for (int jn = 0; jn < 4; ++jn) {
            float a = 0.f;
            #pragma unroll
            for (int j = 0; j < 8; ++j) {
                float xv = (&v[j].x)[jn];
                a += xv * xv;
            }
            x2p[jn] = a;
        }
        #pragma unroll
        for (int jn = 0; jn < 4; ++jn) {
            x2p[jn] += __shfl_xor(x2p[jn], 4);
            x2p[jn] += __shfl_xor(x2p[jn], 8);
            x2p[jn] += __shfl_xor(x2p[jn], 16);
            x2p[jn] += __shfl_xor(x2p[jn], 32);
        }
        // X_dn [d][n_loc]: rotated store order so banks spread across dgrp
        #pragma unroll
        for (int j = 0; j < 8; ++j) {
            int jj = (j + dgrp) & 7;
            unsigned* p = (unsigned*)&X_dn[(dgrp * 8 + jj) * XDN_S + w * 16 + nq * 4];
            p[0] = f2bf_pk(v[jj].x, v[jj].y);
            p[1] = f2bf_pk(v[jj].z, v[jj].w);
        }
        // X_nd [n][d], XOR-swizzled granules (wave-local rows!)
        #pragma unroll
        for (int jn = 0; jn < 4; ++jn) {
            unsigned q[4];
            #pragma unroll
            for (int j2 = 0; j2 < 4; ++j2)
                q[j2] = f2bf_pk((&v[2 * j2].x)[jn], (&v[2 * j2 + 1].x)[jn]);
            int row = w * 16 + nq * 4 + jn;
            *(uint4*)&X_nd[row * 128 + ((dgrp ^ (row & 15)) * 8)] = *(const uint4*)q;
        }
        // wave-local X_nd write->read: no block barrier, just LDS drain + order
        asm volatile("s_waitcnt lgkmcnt(0)" ::: "memory");
        __builtin_amdgcn_wave_barrier();
        // ---- GEMM1: xc[n][k], wave w owns n-rows w*16..+15 (self-staged) ----
        f32x4_t acc1[2];
        acc1[0] = (f32x4_t){0.f, 0.f, 0.f, 0.f};
        acc1[1] = (f32x4_t){0.f, 0.f, 0.f, 0.f};
        #pragma unroll
        for (int ks = 0; ks < 4; ++ks) {
            int g = (ks * 4 + lq) ^ lm;    // swizzled granule
            bf16x8_t a  = *(const bf16x8_t*)&X_nd[(w * 16 + lm) * 128 + g * 8];
            bf16x8_t b0 = *(const bf16x8_t*)&CWb[lm * 128 + g * 8];
            bf16x8_t b1 = *(const bf16x8_t*)&CWb[(16 + lm) * 128 + g * 8];
            acc1[0] = __builtin_amdgcn_mfma_f32_16x16x32_bf16(a, b0, acc1[0], 0, 0, 0);
            acc1[1] = __builtin_amdgcn_mfma_f32_16x16x32_bf16(a, b1, acc1[1], 0, 0, 0);
        }
        // ---- softmax over k; C-layout: col(k)=lm, row(n)=lq*4+r ----
        #pragma unroll
        for (int r = 0; r < 4; ++r) {
            int nl = w * 16 + lq * 4 + r;
            float x2v = __shfl(x2p[r], lq);   // lane lq holds x2 for n-quad lq
            float sl0 = u0 * x2v + w0 - 2.f * u0 * acc1[0][r];
            float sl1 = u1 * x2v + w1 - 2.f * u1 * acc1[1][r];
            float m = fmaxf(sl0, sl1);
            m = fmaxf(m, __shfl_xor(m, 1));
            m = fmaxf(m, __shfl_xor(m, 2));
            m = fmaxf(m, __shfl_xor(m, 4));
            m = fmaxf(m, __shfl_xor(m, 8));
            float p0 = __expf(sl0 - m);
            float p1 = __expf(sl1 - m);
            float sum = p0 + p1;
            sum += __shfl_xor(sum, 1);
            sum += __shfl_xor(sum, 2);
            sum += __shfl_xor(sum, 4);
            sum += __shfl_xor(sum, 8);
            float inv = 1.f / sum;
            p0 *= inv; p1 *= inv;
            ps0 += p0; ps1 += p1;
            Akn[lm * AKN_S + nl] = f2bf(p0);
            Akn[(16 + lm) * AKN_S + nl] = f2bf(p1);
        }
        __syncthreads();   // Akn + X_dn (all waves) ready
        // ---- GEMM2: E[d][k] += X^T[d][n] * A[n][k]; wave w: d-tiles {w, w+4} ----
        #pragma unroll
        for (int ks = 0; ks < 2; ++ks) {
            bf16x8_t xa0 = *(const bf16x8_t*)&X_dn[(w * 16 + lm) * XDN_S + ks * 32 + lq * 8];
            bf16x8_t xa1 = *(const bf16x8_t*)&X_dn[((w + 4) * 16 + lm) * XDN_S + ks * 32 + lq * 8];
            bf16x8_t pb0 = *(const bf16x8_t*)&Akn[lm * AKN_S + ks * 32 + lq * 8];
            bf16x8_t pb1 = *(const bf16x8_t*)&Akn[(16 + lm) * AKN_S + ks * 32 + lq * 8];
            acc2[0][0] = __builtin_amdgcn_mfma_f32_16x16x32_bf16(xa0, pb0, acc2[0][0], 0, 0, 0);
            acc2[0][1] = __builtin_amdgcn_mfma_f32_16x16x32_bf16(xa0, pb1, acc2[0][1], 0, 0, 0);
            acc2[1][0] = __builtin_amdgcn_mfma_f32_16x16x32_bf16(xa1, pb0, acc2[1][0], 0, 0, 0);
            acc2[1][1] = __builtin_amdgcn_mfma_f32_16x16x32_bf16(xa1, pb1, acc2[1][1], 0, 0, 0);
        }
    }

    // ---- block-partial sumA[k] ----
    ps0 += __shfl_xor(ps0, 16); ps0 += __shfl_xor(ps0, 32);
    ps1 += __shfl_xor(ps1, 16); ps1 += __shfl_xor(ps1, 32);
    __syncthreads();           // last GEMM2 done before reusing nothing; order sAw
    if (l < 16) {
        sAw[w * 34 + l] = ps0;
        sAw[w * 34 + 16 + l] = ps1;
    }
    __syncthreads();
    if (t < 32) sA[t] = sAw[t] + sAw[34 + t] + sAw[68 + t] + sAw[102 + t];
    __syncthreads();

    // ---- epilogue: per-block partial (E_partial - sumA_partial * c) -> ws ----
    float* pout = ws + (size_t)blockIdx.x * (K_ * D_);
    #pragma unroll
    for (int di = 0; di < 2; ++di) {
        #pragma unroll
        for (int kt = 0; kt < 2; ++kt) {
            #pragma unroll
            for (int r = 0; r < 4; ++r) {
                int d = (w + di * 4) * 16 + lq * 4 + r;   // C row = M = d
                int k = kt * 16 + lm;                     // C col = N = k
                pout[k * 128 + d] = acc2[di][kt][r] - sA[k] * cw[k * 128 + d];
            }
        }
    }
}

// out[b,k,d] = sum over the 36 block-partials of batch b (deterministic order)
__global__ __launch_bounds__(256) void k_reduce(
        const float* __restrict__ ws, float* __restrict__ out) {
    int i = blockIdx.x * 256 + threadIdx.x;   // float4 index, 0..32767
    int b = i >> 10;                          // 4096/4 = 1024 float4 per batch
    int j = i & 1023;
    const float4* p = (const float4*)ws + (size_t)b * 36 * 1024 + j;
    float4 s = make_float4(0.f, 0.f, 0.f, 0.f);
    #pragma unroll
    for (int c = 0; c < 36; ++c) {
        float4 v = p[(size_t)c * 1024];
        s.x += v.x; s.y += v.y; s.z += v.z; s.w += v.w;
    }
    ((float4*)out)[i] = s;
}

extern "C" void kernel_launch(void* const* d_in, const int* in_sizes, int n_in,
                              void* d_out, int out_size, void* d_ws, size_t ws_size,
                              hipStream_t stream) {
    const float* X     = (const float*)d_in[0];
    const float* cw    = (const float*)d_in[1];
    const float* scale = (const float*)d_in[2];
    float* out = (float*)d_out;
    float* ws  = (float*)d_ws;     // 1152 * 4096 floats = 18.9 MB partials

    k_fused <<<dim3(B_ * 36), dim3(256), 0, stream>>>(X, cw, scale, ws);
    k_reduce<<<dim3(128),     dim3(256), 0, stream>>>(ws, out);
}

// Round 5
// 226.900 us; speedup vs baseline: 1.3945x; 1.3945x over previous
//
#include <hip/hip_runtime.h>

// B=32, D=128, K=32, N=9216. Fused softmax(scaled-L2)+aggregation, bf16 MFMA.
// Deterministic: per-block partials in d_ws + reduction kernel (no atomics).
// R5: round-3 structure + x2 race fix (per-wave redundant x2row),
//     lgkm-only barriers (prefetch loads stay in flight), register prefetch.
#define B_ 32
#define D_ 128
#define K_ 32
#define N_ 9216
#define NT 256      // n per block
#define NS 64       // n per sub-chunk
#define XDN_S 72    // X_dn row stride (bf16 shorts) -> 144 B, 16B-aligned
#define AKN_S 72    // A_kn row stride
#define X2S_S 68    // x2 partial stride (floats)
// X_nd / CWb: stride 128 shorts, 16B-granule XOR swizzle: phys_g = g ^ (row&15)

typedef __bf16 bf16x8_t __attribute__((ext_vector_type(8)));
typedef float f32x4_t __attribute__((ext_vector_type(4)));

__device__ __forceinline__ unsigned short f2bf(float f) {
    unsigned u = __float_as_uint(f);
    u = (u + 0x7fffu + ((u >> 16) & 1u)) >> 16;
    return (unsigned short)u;
}
__device__ __forceinline__ unsigned f2bf_pk(float lo, float hi) {
    unsigned a = __float_as_uint(lo);
    a = (a + 0x7fffu + ((a >> 16) & 1u)) >> 16;
    unsigned b = __float_as_uint(hi);
    b = (b + 0x7fffu + ((b >> 16) & 1u)) & 0xffff0000u;
    return a | b;
}
// Barrier that drains LDS only — leaves global (vmcnt) loads in flight.
// Safe here: in-loop barriers only order LDS traffic; global loads land in
// registers and are waited via compiler-inserted vmcnt at first use.
__device__ __forceinline__ void bar_lds() {
    asm volatile("s_waitcnt lgkmcnt(0)\n\ts_barrier" ::: "memory");
}

__global__ __launch_bounds__(256, 3) void k_fused(
        const float* __restrict__ X, const float* __restrict__ cw,
        const float* __restrict__ scale, float* __restrict__ ws) {
    __shared__ __align__(16) unsigned short X_nd[NS * 128];     // 16384 B (swizzled)
    __shared__ __align__(16) unsigned short X_dn[D_ * XDN_S];   // 18432 B
    __shared__ __align__(16) unsigned short CWb[K_ * 128];      //  8192 B (swizzled)
    __shared__ __align__(16) unsigned short Akn[K_ * AKN_S];    //  4608 B
    __shared__ float x2s[16 * X2S_S];                           //  4352 B
    __shared__ float u_s[K_], w_s[K_];
    __shared__ float sAw[4 * 34];
    __shared__ float sA[K_];

    const int t = threadIdx.x;
    const int w = t >> 6;          // wave 0..3
    const int l = t & 63;          // lane
    const int lm = l & 15;
    const int lq = l >> 4;         // 0..3
    const int d8 = t >> 4;         // staging: d-octet 0..15 (block-spread)
    const int n4 = t & 15;         // staging: n-quad 0..15
    const int b = blockIdx.x / 36;
    const int n0 = (blockIdx.x % 36) * NT;

    // ---- stage codewords -> bf16 LDS (swizzled granules) ----
    #pragma unroll
    for (int i = 0; i < 4; ++i) {
        int idx = t + 256 * i;                 // float4 id, 1024 total
        int k = idx >> 5, d4 = idx & 31;
        float4 c = ((const float4*)cw)[idx];
        int phys = (d4 >> 1) ^ (k & 15);
        unsigned* p = (unsigned*)&CWb[k * 128 + phys * 8 + (d4 & 1) * 4];
        p[0] = f2bf_pk(c.x, c.y);
        p[1] = f2bf_pk(c.z, c.w);
    }
    if (t < 32) {
        float sc = scale[t];
        float s2 = sc * sc;
        const float4* cr = (const float4*)(cw + t * 128);
        float c2 = 0.f;
        #pragma unroll 8
        for (int i = 0; i < 32; ++i) {
            float4 v = cr[i];
            c2 += v.x * v.x + v.y * v.y + v.z * v.z + v.w * v.w;
        }
        u_s[t] = s2;
        w_s[t] = s2 * c2;
    }
    __syncthreads();
    const float u0 = u_s[lm], u1 = u_s[16 + lm];
    const float w0 = w_s[lm], w1 = w_s[16 + lm];

    f32x4_t acc2[2][2];
    #pragma unroll
    for (int a = 0; a < 2; ++a)
        #pragma unroll
        for (int c = 0; c < 2; ++c)
            acc2[a][c] = (f32x4_t){0.f, 0.f, 0.f, 0.f};
    float ps0 = 0.f, ps1 = 0.f;

    // ---- preload sub-chunk 0: thread owns d = d8*8..+7, n = n0 + n4*4..+3 ----
    const float* Xg = X + ((size_t)b * D_ + d8 * 8) * N_ + n0 + n4 * 4;
    float4 v[8];
    #pragma unroll
    for (int j = 0; j < 8; ++j) v[j] = *(const float4*)(Xg + (size_t)j * N_);

    for (int s = 0; s < 4; ++s) {
        bar_lds();   // B1: prev GEMM2 LDS reads done; restage safe
        // ---- prefetch sub-chunk s+1 (stays in flight across barriers) ----
        float4 vn[8];
        if (s < 3) {
            const float* Xg2 = Xg + (s + 1) * NS;
            #pragma unroll
            for (int j = 0; j < 8; ++j) vn[j] = *(const float4*)(Xg2 + (size_t)j * N_);
        }
        // ---- x2 partials (fp32): sum over this thread's 8 d ----
        #pragma unroll
        for (int jn = 0; jn < 4; ++jn) {
            float a = 0.f;
            #pragma unroll
            for (int j = 0; j < 8; ++j) {
                float xv = (&v[j].x)[jn];
                a += xv * xv;
            }
            x2s[d8 * X2S_S + n4 * 4 + jn] = a;
        }
        // ---- X_dn [d][n_loc] ----
        #pragma unroll
        for (int j = 0; j < 8; ++j) {
            unsigned* p = (unsigned*)&X_dn[(d8 * 8 + j) * XDN_S + n4 * 4];
            p[0] = f2bf_pk(v[j].x, v[j].y);
            p[1] = f2bf_pk(v[j].z, v[j].w);
        }
        // ---- X_nd [n][d], XOR-swizzled granules ----
        #pragma unroll
        for (int jn = 0; jn < 4; ++jn) {
            unsigned q[4];
            #pragma unroll
            for (int j2 = 0; j2 < 4; ++j2)
                q[j2] = f2bf_pk((&v[2 * j2].x)[jn], (&v[2 * j2 + 1].x)[jn]);
            int row = n4 * 4 + jn;
            *(uint4*)&X_nd[row * 128 + ((d8 ^ (row & 15)) * 8)] = *(const uint4*)q;
        }
        bar_lds();   // B2: staging visible to all waves
        // ---- per-wave redundant x2row: lane l holds x2 of local row l ----
        // (fixes the cross-wave x2f race: no wave reads another wave's result)
        float x2row = 0.f;
        #pragma unroll
        for (int g = 0; g < 16; ++g) x2row += x2s[g * X2S_S + l];
        // ---- GEMM1: xc[n][k], wave w owns n-rows w*16..+15 ----
        f32x4_t acc1[2];
        acc1[0] = (f32x4_t){0.f, 0.f, 0.f, 0.f};
        acc1[1] = (f32x4_t){0.f, 0.f, 0.f, 0.f};
        #pragma unroll
        for (int ks = 0; ks < 4; ++ks) {
            int g = (ks * 4 + lq) ^ lm;    // swizzled granule
            bf16x8_t a  = *(const bf16x8_t*)&X_nd[(w * 16 + lm) * 128 + g * 8];
            bf16x8_t b0 = *(const bf16x8_t*)&CWb[lm * 128 + g * 8];
            bf16x8_t b1 = *(const bf16x8_t*)&CWb[(16 + lm) * 128 + g * 8];
            acc1[0] = __builtin_amdgcn_mfma_f32_16x16x32_bf16(a, b0, acc1[0], 0, 0, 0);
            acc1[1] = __builtin_amdgcn_mfma_f32_16x16x32_bf16(a, b1, acc1[1], 0, 0, 0);
        }
        // ---- softmax over k; C-layout: col(k)=lm, row(n)=lq*4+r ----
        #pragma unroll
        for (int r = 0; r < 4; ++r) {
            int nl = w * 16 + lq * 4 + r;
            float x2v = __shfl(x2row, lq * 4 + r + w * 16 - w * 16);  // local row
            x2v = __shfl(x2row, lq * 4 + r);   // row l within this wave's table?
            // NOTE: x2row tables are per-wave over *global* local rows 0..63:
            // lane l holds row l, so the row we need is nl itself.
            x2v = __shfl(x2row, nl);
            float sl0 = u0 * x2v + w0 - 2.f * u0 * acc1[0][r];
            float sl1 = u1 * x2v + w1 - 2.f * u1 * acc1[1][r];
            float m = fmaxf(sl0, sl1);
            m = fmaxf(m, __shfl_xor(m, 1));
            m = fmaxf(m, __shfl_xor(m, 2));
            m = fmaxf(m, __shfl_xor(m, 4));
            m = fmaxf(m, __shfl_xor(m, 8));
            float p0 = __expf(sl0 - m);
            float p1 = __expf(sl1 - m);
            float sum = p0 + p1;
            sum += __shfl_xor(sum, 1);
            sum += __shfl_xor(sum, 2);
            sum += __shfl_xor(sum, 4);
            sum += __shfl_xor(sum, 8);
            float inv = 1.f / sum;
            p0 *= inv; p1 *= inv;
            ps0 += p0; ps1 += p1;
            Akn[lm * AKN_S + nl] = f2bf(p0);
            Akn[(16 + lm) * AKN_S + nl] = f2bf(p1);
        }
        bar_lds();   // B3: Akn visible
        // ---- GEMM2: E[d][k] += X^T[d][n] * A[n][k]; wave w: d-tiles {w, w+4} ----
        #pragma unroll
        for (int ks = 0; ks < 2; ++ks) {
            bf16x8_t xa0 = *(const bf16x8_t*)&X_dn[(w * 16 + lm) * XDN_S + ks * 32 + lq * 8];
            bf16x8_t xa1 = *(const bf16x8_t*)&X_dn[((w + 4) * 16 + lm) * XDN_S + ks * 32 + lq * 8];
            bf16x8_t pb0 = *(const bf16x8_t*)&Akn[lm * AKN_S + ks * 32 + lq * 8];
            bf16x8_t pb1 = *(const bf16x8_t*)&Akn[(16 + lm) * AKN_S + ks * 32 + lq * 8];
            acc2[0][0] = __builtin_amdgcn_mfma_f32_16x16x32_bf16(xa0, pb0, acc2[0][0], 0, 0, 0);
            acc2[0][1] = __builtin_amdgcn_mfma_f32_16x16x32_bf16(xa0, pb1, acc2[0][1], 0, 0, 0);
            acc2[1][0] = __builtin_amdgcn_mfma_f32_16x16x32_bf16(xa1, pb0, acc2[1][0], 0, 0, 0);
            acc2[1][1] = __builtin_amdgcn_mfma_f32_16x16x32_bf16(xa1, pb1, acc2[1][1], 0, 0, 0);
        }
        if (s < 3) {
            #pragma unroll
            for (int j = 0; j < 8; ++j) v[j] = vn[j];
        }
    }

    // ---- block-partial sumA[k] ----
    ps0 += __shfl_xor(ps0, 16); ps0 += __shfl_xor(ps0, 32);
    ps1 += __shfl_xor(ps1, 16); ps1 += __shfl_xor(ps1, 32);
    __syncthreads();
    if (l < 16) {
        sAw[w * 34 + l] = ps0;
        sAw[w * 34 + 16 + l] = ps1;
    }
    __syncthreads();
    if (t < 32) sA[t] = sAw[t] + sAw[34 + t] + sAw[68 + t] + sAw[102 + t];
    __syncthreads();

    // ---- epilogue: per-block partial (E_partial - sumA_partial * c) -> ws ----
    float* pout = ws + (size_t)blockIdx.x * (K_ * D_);
    #pragma unroll
    for (int di = 0; di < 2; ++di) {
        #pragma unroll
        for (int kt = 0; kt < 2; ++kt) {
            const int d0 = (w + di * 4) * 16 + lq * 4;   // C row = M = d
            const int k  = kt * 16 + lm;                 // C col = N = k
            float4 o;
            #pragma unroll
            for (int r = 0; r < 4; ++r)
                (&o.x)[r] = acc2[di][kt][r] - sA[k] * cw[k * 128 + d0 + r];
            *(float4*)&pout[k * 128 + d0] = o;
        }
    }
}

// out[b,k,d] = sum over the 36 block-partials of batch b (deterministic order)
__global__ __launch_bounds__(256) void k_reduce(
        const float* __restrict__ ws, float* __restrict__ out) {
    int i = blockIdx.x * 256 + threadIdx.x;   // float4 index, 0..32767
    int b = i >> 10;                          // 4096/4 = 1024 float4 per batch
    int j = i & 1023;
    const float4* p = (const float4*)ws + (size_t)b * 36 * 1024 + j;
    float4 s = make_float4(0.f, 0.f, 0.f, 0.f);
    #pragma unroll
    for (int c = 0; c < 36; ++c) {
        float4 v = p[(size_t)c * 1024];
        s.x += v.x; s.y += v.y; s.z += v.z; s.w += v.w;
    }
    ((float4*)out)[i] = s;
}

extern "C" void kernel_launch(void* const* d_in, const int* in_sizes, int n_in,
                              void* d_out, int out_size, void* d_ws, size_t ws_size,
                              hipStream_t stream) {
    const float* X     = (const float*)d_in[0];
    const float* cw    = (const float*)d_in[1];
    const float* scale = (const float*)d_in[2];
    float* out = (float*)d_out;
    float* ws  = (float*)d_ws;     // 1152 * 4096 floats = 18.9 MB partials

    k_fused <<<dim3(B_ * 36), dim3(256), 0, stream>>>(X, cw, scale, ws);
    k_reduce<<<dim3(128),     dim3(256), 0, stream>>>(ws, out);
}